// Round 1
// baseline (173.481 us; speedup 1.0000x reference)
//
#include <hip/hip_runtime.h>

// ---------------------------------------------------------------------------
// PlainSelfAttention (2quad, tau-scaled) on MI355X.
//  x[2,2048,1024] fp32, Wqkv[1024,3072], Wo[1024,1024], tau[16]
//  qkv GEMM -> per-head (s/(8*tau)+5)^2 attention (non-softmax, streaming)
//  -> Wo GEMM. All GEMMs bf16 MFMA (16x16x32) with fp32 accumulation.
// ---------------------------------------------------------------------------

typedef unsigned short ushort_t;
typedef __attribute__((ext_vector_type(8))) short short8;
typedef __attribute__((ext_vector_type(4))) float f32x4;

#define B_      2
#define T_      2048
#define C_      1024
#define HEADS_  16
#define D_      64
#define M_      (B_ * T_)     // 4096
#define N3_     (3 * C_)      // 3072

__device__ __forceinline__ ushort_t f2bf(float f) {
  union { float f; unsigned u; } v; v.f = f;
  unsigned r = v.u + 0x7FFFu + ((v.u >> 16) & 1u);   // RNE
  return (ushort_t)(r >> 16);
}

// -------------------------- cast x (fp32 -> bf16) --------------------------
__global__ __launch_bounds__(256) void cast_x_kernel(const float* __restrict__ x,
                                                     ushort_t* __restrict__ xb) {
  int i = blockIdx.x * 256 + threadIdx.x;           // grid sized exactly
  float4 f = ((const float4*)x)[i];
  ushort_t* o = xb + (size_t)i * 4;
  o[0] = f2bf(f.x); o[1] = f2bf(f.y); o[2] = f2bf(f.z); o[3] = f2bf(f.w);
}

// ------------------ transpose + cast weights (fp32->bf16) ------------------
// in: [R][Cc] fp32   out: [Cc][R] bf16
__global__ __launch_bounds__(256) void transpose_cast_w(const float* __restrict__ in,
                                                        ushort_t* __restrict__ out,
                                                        int R, int Cc) {
  __shared__ float tile[64][65];
  int rb = blockIdx.y, cb = blockIdx.x;
  int c = threadIdx.x & 63;
  int r0 = threadIdx.x >> 6;
#pragma unroll
  for (int i = 0; i < 16; ++i) {
    int r = r0 + i * 4;
    tile[r][c] = in[(size_t)(rb * 64 + r) * Cc + cb * 64 + c];
  }
  __syncthreads();
#pragma unroll
  for (int i = 0; i < 16; ++i) {
    int r = r0 + i * 4;
    out[(size_t)(cb * 64 + r) * R + rb * 64 + c] = f2bf(tile[c][r]);
  }
}

// ------------------------- transpose v -> vT (bf16) ------------------------
// v: [BH][T][64]  ->  vT: [BH][64][T]
__global__ __launch_bounds__(256) void transpose_v_kernel(const ushort_t* __restrict__ v,
                                                          ushort_t* __restrict__ vT) {
  __shared__ ushort_t tile[64][72];
  int bh = blockIdx.y, tb = blockIdx.x;
  int c = threadIdx.x & 63;
  int r0 = threadIdx.x >> 6;
#pragma unroll
  for (int i = 0; i < 16; ++i) {
    int r = r0 + i * 4;
    tile[r][c] = v[((size_t)bh * T_ + tb * 64 + r) * D_ + c];
  }
  __syncthreads();
#pragma unroll
  for (int i = 0; i < 16; ++i) {
    int r = r0 + i * 4;
    vT[((size_t)bh * D_ + r) * T_ + tb * 64 + c] = tile[c][r];
  }
}

// -------------------- shared GEMM mainloop (bf16 MFMA) ---------------------
// A: [M][K] bf16 row-major; Bt: [N][K] bf16 row-major (B transposed).
// 128x128 tile, BK=64, 256 threads (4 waves, 2x2 of 64x64 per wave).
// LDS rows padded to 72 elems (144 B) -> fragment ds_read_b128 is <=2-way
// bank aliasing (free).
__device__ __forceinline__ void gemm_tile(const ushort_t* __restrict__ A,
                                          const ushort_t* __restrict__ Bt,
                                          int K, int tm, int tn,
                                          ushort_t* lds, f32x4 acc[4][4]) {
  const int tid = threadIdx.x;
  const int lane = tid & 63, wave = tid >> 6;
  const int wm = wave >> 1, wn = wave & 1;
  const int lr = lane & 15, lk = lane >> 4;
  ushort_t* As = lds;               // [128][72]
  ushort_t* Bs = lds + 128 * 72;    // [128][72]
  const ushort_t* Ag = A + (size_t)tm * 128 * K;
  const ushort_t* Bg = Bt + (size_t)tn * 128 * K;

  for (int kt = 0; kt < K; kt += 64) {
#pragma unroll
    for (int i = 0; i < 4; ++i) {
      int cch = tid + i * 256; int row = cch >> 3, kc = cch & 7;
      *(short8*)&As[row * 72 + kc * 8] =
          *(const short8*)&Ag[(size_t)row * K + kt + kc * 8];
    }
#pragma unroll
    for (int i = 0; i < 4; ++i) {
      int cch = tid + i * 256; int row = cch >> 3, kc = cch & 7;
      *(short8*)&Bs[row * 72 + kc * 8] =
          *(const short8*)&Bg[(size_t)row * K + kt + kc * 8];
    }
    __syncthreads();
#pragma unroll
    for (int kk = 0; kk < 64; kk += 32) {
      short8 a[4], b[4];
#pragma unroll
      for (int m = 0; m < 4; ++m)
        a[m] = *(const short8*)&As[(wm * 64 + m * 16 + lr) * 72 + kk + lk * 8];
#pragma unroll
      for (int n = 0; n < 4; ++n)
        b[n] = *(const short8*)&Bs[(wn * 64 + n * 16 + lr) * 72 + kk + lk * 8];
#pragma unroll
      for (int m = 0; m < 4; ++m)
#pragma unroll
        for (int n = 0; n < 4; ++n)
          acc[m][n] = __builtin_amdgcn_mfma_f32_16x16x32_bf16(a[m], b[n], acc[m][n], 0, 0, 0);
    }
    __syncthreads();
  }
}

// -------------------- GEMM1: qkv = xb @ Wqkv^T, scatter --------------------
// Output scattered as bf16 into q/k/v tensors laid out [B*H][T][64].
__global__ __launch_bounds__(256) void gemm_qkv(const ushort_t* __restrict__ xb,
                                                const ushort_t* __restrict__ wT,
                                                ushort_t* __restrict__ qg,
                                                ushort_t* __restrict__ kg,
                                                ushort_t* __restrict__ vg) {
  __shared__ __align__(16) ushort_t lds[2 * 128 * 72];
  f32x4 acc[4][4];
#pragma unroll
  for (int m = 0; m < 4; ++m)
#pragma unroll
    for (int n = 0; n < 4; ++n) acc[m][n] = (f32x4){0.f, 0.f, 0.f, 0.f};

  gemm_tile(xb, wT, C_, blockIdx.y, blockIdx.x, lds, acc);

  const int lane = threadIdx.x & 63, wave = threadIdx.x >> 6;
  const int wm = wave >> 1, wn = wave & 1;
  const int lr = lane & 15, lk = lane >> 4;
#pragma unroll
  for (int m = 0; m < 4; ++m)
#pragma unroll
    for (int n = 0; n < 4; ++n)
#pragma unroll
      for (int r = 0; r < 4; ++r) {
        int row = blockIdx.y * 128 + wm * 64 + m * 16 + lk * 4 + r;  // = b*T + t
        int col = blockIdx.x * 128 + wn * 64 + n * 16 + lr;          // [0,3072)
        int b = row >> 11, t = row & 2047;
        int part = col >> 10, idx = col & 1023;
        int h = idx >> 6, j = idx & 63;
        ushort_t* dst = (part == 0) ? qg : (part == 1) ? kg : vg;
        dst[(((size_t)(b * HEADS_ + h)) * T_ + t) * D_ + j] = f2bf(acc[m][n][r]);
      }
}

// ---------------------- GEMM2: out = attn_bf16 @ Wo^T ----------------------
__global__ __launch_bounds__(256) void gemm_out(const ushort_t* __restrict__ ab,
                                                const ushort_t* __restrict__ woT,
                                                float* __restrict__ out) {
  __shared__ __align__(16) ushort_t lds[2 * 128 * 72];
  f32x4 acc[4][4];
#pragma unroll
  for (int m = 0; m < 4; ++m)
#pragma unroll
    for (int n = 0; n < 4; ++n) acc[m][n] = (f32x4){0.f, 0.f, 0.f, 0.f};

  gemm_tile(ab, woT, C_, blockIdx.y, blockIdx.x, lds, acc);

  const int lane = threadIdx.x & 63, wave = threadIdx.x >> 6;
  const int wm = wave >> 1, wn = wave & 1;
  const int lr = lane & 15, lk = lane >> 4;
#pragma unroll
  for (int m = 0; m < 4; ++m)
#pragma unroll
    for (int n = 0; n < 4; ++n)
#pragma unroll
      for (int r = 0; r < 4; ++r) {
        int row = blockIdx.y * 128 + wm * 64 + m * 16 + lk * 4 + r;
        int col = blockIdx.x * 128 + wn * 64 + n * 16 + lr;
        out[(size_t)row * C_ + col] = acc[m][n][r];
      }
}

// --------------------------- fused 2quad attention -------------------------
// One block = (bh, 128 q-rows). 4 waves x 32 q-rows. KV tile = 64.
// Streaming: numer += E@V, denom += rowsum(E); no max tracking needed
// (e = (s/(8*tau)+5)^2 >= 0, bounded).
__global__ __launch_bounds__(256) void attn_kernel(const ushort_t* __restrict__ qg,
                                                   const ushort_t* __restrict__ kg,
                                                   const ushort_t* __restrict__ vTg,
                                                   const float* __restrict__ tau,
                                                   ushort_t* __restrict__ attn_out) {
  __shared__ __align__(16) ushort_t Ks[64 * 72];
  __shared__ __align__(16) ushort_t Vts[64 * 72];
  __shared__ __align__(16) ushort_t Es[4][32 * 72];

  const int tid = threadIdx.x, lane = tid & 63, w = tid >> 6;
  const int lr = lane & 15, lk = lane >> 4;
  const int qt = blockIdx.x, bh = blockIdx.y;
  const int b = bh >> 4, h = bh & 15;
  const float inv = 1.0f / (8.0f * tau[h]);   // sqrt(64)*tau

  const ushort_t* qb = qg + ((size_t)bh * T_ + qt * 128 + w * 32) * D_;
  const ushort_t* kb = kg + (size_t)bh * T_ * D_;
  const ushort_t* vb = vTg + (size_t)bh * D_ * T_;

  // Q fragments held in registers for the whole block (loop-invariant).
  short8 qa[2][2];
#pragma unroll
  for (int m = 0; m < 2; ++m)
#pragma unroll
    for (int ks = 0; ks < 2; ++ks)
      qa[m][ks] = *(const short8*)&qb[(m * 16 + lr) * D_ + ks * 32 + lk * 8];

  f32x4 acc[2][4];
  float denom[2][4];
#pragma unroll
  for (int m = 0; m < 2; ++m) {
#pragma unroll
    for (int n = 0; n < 4; ++n) acc[m][n] = (f32x4){0.f, 0.f, 0.f, 0.f};
#pragma unroll
    for (int r = 0; r < 4; ++r) denom[m][r] = 0.f;
  }

  for (int kv = 0; kv < T_; kv += 64) {
    // stage K tile [64][64] and Vt tile [64][64] (padded rows)
#pragma unroll
    for (int i = 0; i < 2; ++i) {
      int cch = tid + i * 256; int row = cch >> 3, kc = cch & 7;
      *(short8*)&Ks[row * 72 + kc * 8] =
          *(const short8*)&kb[(size_t)(kv + row) * D_ + kc * 8];
      *(short8*)&Vts[row * 72 + kc * 8] =
          *(const short8*)&vb[(size_t)row * T_ + kv + kc * 8];
    }
    __syncthreads();

    // S = Q @ K^T  (raw q.k accumulated fp32)
    f32x4 s[2][4];
#pragma unroll
    for (int m = 0; m < 2; ++m)
#pragma unroll
      for (int n = 0; n < 4; ++n) s[m][n] = (f32x4){0.f, 0.f, 0.f, 0.f};
#pragma unroll
    for (int kk = 0; kk < 2; ++kk) {
      short8 bk[4];
#pragma unroll
      for (int n = 0; n < 4; ++n)
        bk[n] = *(const short8*)&Ks[(n * 16 + lr) * 72 + kk * 32 + lk * 8];
#pragma unroll
      for (int m = 0; m < 2; ++m)
#pragma unroll
        for (int n = 0; n < 4; ++n)
          s[m][n] = __builtin_amdgcn_mfma_f32_16x16x32_bf16(qa[m][kk], bk[n], s[m][n], 0, 0, 0);
    }

    // e = (s*inv + 5)^2 ; rowsum ; stash bf16 E into per-wave LDS region
    float rs[2][4];
#pragma unroll
    for (int m = 0; m < 2; ++m)
#pragma unroll
      for (int r = 0; r < 4; ++r) rs[m][r] = 0.f;
#pragma unroll
    for (int m = 0; m < 2; ++m)
#pragma unroll
      for (int n = 0; n < 4; ++n)
#pragma unroll
        for (int r = 0; r < 4; ++r) {
          float t = s[m][n][r] * inv + 5.0f;
          float e = t * t;
          rs[m][r] += e;
          Es[w][(m * 16 + lk * 4 + r) * 72 + n * 16 + lr] = f2bf(e);
        }
    // reduce rowsum across the 16-lane column group, accumulate denom
#pragma unroll
    for (int m = 0; m < 2; ++m)
#pragma unroll
      for (int r = 0; r < 4; ++r) {
        float v = rs[m][r];
        v += __shfl_xor(v, 1); v += __shfl_xor(v, 2);
        v += __shfl_xor(v, 4); v += __shfl_xor(v, 8);
        denom[m][r] += v;
      }

    // PV: acc += E @ V   (A-frags from per-wave Es, B-frags from Vt)
#pragma unroll
    for (int kk = 0; kk < 2; ++kk) {
      short8 ea[2], vv[4];
#pragma unroll
      for (int m = 0; m < 2; ++m)
        ea[m] = *(const short8*)&Es[w][(m * 16 + lr) * 72 + kk * 32 + lk * 8];
#pragma unroll
      for (int n = 0; n < 4; ++n)
        vv[n] = *(const short8*)&Vts[(n * 16 + lr) * 72 + kk * 32 + lk * 8];
#pragma unroll
      for (int m = 0; m < 2; ++m)
#pragma unroll
        for (int n = 0; n < 4; ++n)
          acc[m][n] = __builtin_amdgcn_mfma_f32_16x16x32_bf16(ea[m], vv[n], acc[m][n], 0, 0, 0);
    }
    __syncthreads();
  }

  // epilogue: divide by (denom + eps), write bf16 attn_out [B*T][C]
#pragma unroll
  for (int m = 0; m < 2; ++m)
#pragma unroll
    for (int n = 0; n < 4; ++n)
#pragma unroll
      for (int r = 0; r < 4; ++r) {
        int qrow = qt * 128 + w * 32 + m * 16 + lk * 4 + r;
        int d = n * 16 + lr;
        float o = acc[m][n][r] / (denom[m][r] + 1e-6f);
        attn_out[((size_t)(b * T_ + qrow)) * C_ + h * D_ + d] = f2bf(o);
      }
}

// ---------------------------------------------------------------------------
extern "C" void kernel_launch(void* const* d_in, const int* in_sizes, int n_in,
                              void* d_out, int out_size, void* d_ws, size_t ws_size,
                              hipStream_t stream) {
  const float* x    = (const float*)d_in[0];
  const float* Wqkv = (const float*)d_in[1];
  const float* Wo   = (const float*)d_in[2];
  const float* tau  = (const float*)d_in[3];
  float* out = (float*)d_out;

  char* ws = (char*)d_ws;
  ushort_t* xb    = (ushort_t*)(ws);                 //  8,388,608 B
  ushort_t* wqkvT = (ushort_t*)(ws + 8388608);       //  6,291,456 B
  ushort_t* woT   = (ushort_t*)(ws + 14680064);      //  2,097,152 B
  ushort_t* qg    = (ushort_t*)(ws + 16777216);      //  8,388,608 B
  ushort_t* kg    = (ushort_t*)(ws + 25165824);      //  8,388,608 B
  ushort_t* ab    = (ushort_t*)(ws + 33554432);      //  8,388,608 B  (total ~42 MB)
  // v and vT scratch live in d_out (16,777,216 B) — consumed before gemm_out
  // overwrites d_out with the final fp32 result.
  ushort_t* vg  = (ushort_t*)d_out;
  ushort_t* vTg = (ushort_t*)d_out + 4194304;

  cast_x_kernel<<<4096, 256, 0, stream>>>(x, xb);
  transpose_cast_w<<<dim3(48, 16), 256, 0, stream>>>(Wqkv, wqkvT, 1024, 3072);
  transpose_cast_w<<<dim3(16, 16), 256, 0, stream>>>(Wo, woT, 1024, 1024);
  gemm_qkv<<<dim3(24, 32), 256, 0, stream>>>(xb, wqkvT, qg, kg, vg);
  transpose_v_kernel<<<dim3(32, 32), 256, 0, stream>>>(vg, vTg);
  attn_kernel<<<dim3(16, 32), 256, 0, stream>>>(qg, kg, vTg, tau, ab);
  gemm_out<<<dim3(8, 32), 256, 0, stream>>>(ab, woT, out);
}

// Round 2
// 155.788 us; speedup vs baseline: 1.1136x; 1.1136x over previous
//
#include <hip/hip_runtime.h>
#include <hip/hip_bf16.h>

// ---------------------------------------------------------------------------
// PlainSelfAttention (2quad, tau-scaled) on MI355X.
//  x[2,2048,1024] fp32, Wqkv[1024,3072], Wo[1024,1024], tau[16]
//  qkv GEMM -> per-head (s/(8*tau)+5)^2 attention (non-softmax, streaming)
//  -> Wo GEMM. All GEMMs bf16 MFMA (16x16x32) with fp32 accumulation.
// R2: attn occupancy 21%->~50% (64-row q-tiles, grid 32x32), deferred denom
//     reduce (epilogue-only shfl), 1-op bf16 casts.
// ---------------------------------------------------------------------------

typedef unsigned short ushort_t;
typedef __attribute__((ext_vector_type(8))) short short8;
typedef __attribute__((ext_vector_type(4))) float f32x4;

#define B_      2
#define T_      2048
#define C_      1024
#define HEADS_  16
#define D_      64
#define M_      (B_ * T_)     // 4096
#define N3_     (3 * C_)      // 3072

__device__ __forceinline__ ushort_t f2bf(float f) {
  __hip_bfloat16 h = __float2bfloat16(f);           // RNE, v_cvt_pk_bf16_f32
  return *reinterpret_cast<ushort_t*>(&h);
}

// -------------------------- cast x (fp32 -> bf16) --------------------------
__global__ __launch_bounds__(256) void cast_x_kernel(const float* __restrict__ x,
                                                     ushort_t* __restrict__ xb) {
  int i = blockIdx.x * 256 + threadIdx.x;           // grid sized exactly
  float4 f = ((const float4*)x)[i];
  ushort_t* o = xb + (size_t)i * 4;
  o[0] = f2bf(f.x); o[1] = f2bf(f.y); o[2] = f2bf(f.z); o[3] = f2bf(f.w);
}

// ------------------ transpose + cast weights (fp32->bf16) ------------------
// in: [R][Cc] fp32   out: [Cc][R] bf16
__global__ __launch_bounds__(256) void transpose_cast_w(const float* __restrict__ in,
                                                        ushort_t* __restrict__ out,
                                                        int R, int Cc) {
  __shared__ float tile[64][65];
  int rb = blockIdx.y, cb = blockIdx.x;
  int c = threadIdx.x & 63;
  int r0 = threadIdx.x >> 6;
#pragma unroll
  for (int i = 0; i < 16; ++i) {
    int r = r0 + i * 4;
    tile[r][c] = in[(size_t)(rb * 64 + r) * Cc + cb * 64 + c];
  }
  __syncthreads();
#pragma unroll
  for (int i = 0; i < 16; ++i) {
    int r = r0 + i * 4;
    out[(size_t)(cb * 64 + r) * R + rb * 64 + c] = f2bf(tile[c][r]);
  }
}

// ------------------------- transpose v -> vT (bf16) ------------------------
// v: [BH][T][64]  ->  vT: [BH][64][T]
__global__ __launch_bounds__(256) void transpose_v_kernel(const ushort_t* __restrict__ v,
                                                          ushort_t* __restrict__ vT) {
  __shared__ ushort_t tile[64][72];
  int bh = blockIdx.y, tb = blockIdx.x;
  int c = threadIdx.x & 63;
  int r0 = threadIdx.x >> 6;
#pragma unroll
  for (int i = 0; i < 16; ++i) {
    int r = r0 + i * 4;
    tile[r][c] = v[((size_t)bh * T_ + tb * 64 + r) * D_ + c];
  }
  __syncthreads();
#pragma unroll
  for (int i = 0; i < 16; ++i) {
    int r = r0 + i * 4;
    vT[((size_t)bh * D_ + r) * T_ + tb * 64 + c] = tile[c][r];
  }
}

// -------------------- shared GEMM mainloop (bf16 MFMA) ---------------------
// A: [M][K] bf16 row-major; Bt: [N][K] bf16 row-major (B transposed).
// 128x128 tile, BK=64, 256 threads (4 waves, 2x2 of 64x64 per wave).
__device__ __forceinline__ void gemm_tile(const ushort_t* __restrict__ A,
                                          const ushort_t* __restrict__ Bt,
                                          int K, int tm, int tn,
                                          ushort_t* lds, f32x4 acc[4][4]) {
  const int tid = threadIdx.x;
  const int lane = tid & 63, wave = tid >> 6;
  const int wm = wave >> 1, wn = wave & 1;
  const int lr = lane & 15, lk = lane >> 4;
  ushort_t* As = lds;               // [128][72]
  ushort_t* Bs = lds + 128 * 72;    // [128][72]
  const ushort_t* Ag = A + (size_t)tm * 128 * K;
  const ushort_t* Bg = Bt + (size_t)tn * 128 * K;

  for (int kt = 0; kt < K; kt += 64) {
#pragma unroll
    for (int i = 0; i < 4; ++i) {
      int cch = tid + i * 256; int row = cch >> 3, kc = cch & 7;
      *(short8*)&As[row * 72 + kc * 8] =
          *(const short8*)&Ag[(size_t)row * K + kt + kc * 8];
    }
#pragma unroll
    for (int i = 0; i < 4; ++i) {
      int cch = tid + i * 256; int row = cch >> 3, kc = cch & 7;
      *(short8*)&Bs[row * 72 + kc * 8] =
          *(const short8*)&Bg[(size_t)row * K + kt + kc * 8];
    }
    __syncthreads();
#pragma unroll
    for (int kk = 0; kk < 64; kk += 32) {
      short8 a[4], b[4];
#pragma unroll
      for (int m = 0; m < 4; ++m)
        a[m] = *(const short8*)&As[(wm * 64 + m * 16 + lr) * 72 + kk + lk * 8];
#pragma unroll
      for (int n = 0; n < 4; ++n)
        b[n] = *(const short8*)&Bs[(wn * 64 + n * 16 + lr) * 72 + kk + lk * 8];
#pragma unroll
      for (int m = 0; m < 4; ++m)
#pragma unroll
        for (int n = 0; n < 4; ++n)
          acc[m][n] = __builtin_amdgcn_mfma_f32_16x16x32_bf16(a[m], b[n], acc[m][n], 0, 0, 0);
    }
    __syncthreads();
  }
}

// -------------------- GEMM1: qkv = xb @ Wqkv^T, scatter --------------------
__global__ __launch_bounds__(256) void gemm_qkv(const ushort_t* __restrict__ xb,
                                                const ushort_t* __restrict__ wT,
                                                ushort_t* __restrict__ qg,
                                                ushort_t* __restrict__ kg,
                                                ushort_t* __restrict__ vg) {
  __shared__ __align__(16) ushort_t lds[2 * 128 * 72];
  f32x4 acc[4][4];
#pragma unroll
  for (int m = 0; m < 4; ++m)
#pragma unroll
    for (int n = 0; n < 4; ++n) acc[m][n] = (f32x4){0.f, 0.f, 0.f, 0.f};

  gemm_tile(xb, wT, C_, blockIdx.y, blockIdx.x, lds, acc);

  const int lane = threadIdx.x & 63, wave = threadIdx.x >> 6;
  const int wm = wave >> 1, wn = wave & 1;
  const int lr = lane & 15, lk = lane >> 4;
#pragma unroll
  for (int m = 0; m < 4; ++m)
#pragma unroll
    for (int n = 0; n < 4; ++n)
#pragma unroll
      for (int r = 0; r < 4; ++r) {
        int row = blockIdx.y * 128 + wm * 64 + m * 16 + lk * 4 + r;  // = b*T + t
        int col = blockIdx.x * 128 + wn * 64 + n * 16 + lr;          // [0,3072)
        int b = row >> 11, t = row & 2047;
        int part = col >> 10, idx = col & 1023;
        int h = idx >> 6, j = idx & 63;
        ushort_t* dst = (part == 0) ? qg : (part == 1) ? kg : vg;
        dst[(((size_t)(b * HEADS_ + h)) * T_ + t) * D_ + j] = f2bf(acc[m][n][r]);
      }
}

// ---------------------- GEMM2: out = attn_bf16 @ Wo^T ----------------------
__global__ __launch_bounds__(256) void gemm_out(const ushort_t* __restrict__ ab,
                                                const ushort_t* __restrict__ woT,
                                                float* __restrict__ out) {
  __shared__ __align__(16) ushort_t lds[2 * 128 * 72];
  f32x4 acc[4][4];
#pragma unroll
  for (int m = 0; m < 4; ++m)
#pragma unroll
    for (int n = 0; n < 4; ++n) acc[m][n] = (f32x4){0.f, 0.f, 0.f, 0.f};

  gemm_tile(ab, woT, C_, blockIdx.y, blockIdx.x, lds, acc);

  const int lane = threadIdx.x & 63, wave = threadIdx.x >> 6;
  const int wm = wave >> 1, wn = wave & 1;
  const int lr = lane & 15, lk = lane >> 4;
#pragma unroll
  for (int m = 0; m < 4; ++m)
#pragma unroll
    for (int n = 0; n < 4; ++n)
#pragma unroll
      for (int r = 0; r < 4; ++r) {
        int row = blockIdx.y * 128 + wm * 64 + m * 16 + lk * 4 + r;
        int col = blockIdx.x * 128 + wn * 64 + n * 16 + lr;
        out[(size_t)row * C_ + col] = acc[m][n][r];
      }
}

// --------------------------- fused 2quad attention -------------------------
// One block = (bh, 64 q-rows). 4 waves x 16 q-rows. KV tile = 64.
// Streaming: numer += E@V, denom(per-lane partial) += rowsum(E); e >= 0 so
// no max tracking. Denom cross-lane reduce deferred to epilogue (linear).
__global__ __launch_bounds__(256) void attn_kernel(const ushort_t* __restrict__ qg,
                                                   const ushort_t* __restrict__ kg,
                                                   const ushort_t* __restrict__ vTg,
                                                   const float* __restrict__ tau,
                                                   ushort_t* __restrict__ attn_out) {
  __shared__ __align__(16) ushort_t Ks[64 * 72];
  __shared__ __align__(16) ushort_t Vts[64 * 72];
  __shared__ __align__(16) ushort_t Es[4][16 * 72];

  const int tid = threadIdx.x, lane = tid & 63, w = tid >> 6;
  const int lr = lane & 15, lk = lane >> 4;
  const int qt = blockIdx.x, bh = blockIdx.y;
  const int b = bh >> 4, h = bh & 15;
  const float inv = 1.0f / (8.0f * tau[h]);   // sqrt(64)*tau

  const ushort_t* qb = qg + ((size_t)bh * T_ + qt * 64 + w * 16) * D_;
  const ushort_t* kb = kg + (size_t)bh * T_ * D_;
  const ushort_t* vb = vTg + (size_t)bh * D_ * T_;

  // Q fragments held in registers for the whole block (loop-invariant).
  short8 qa[2];
#pragma unroll
  for (int ks = 0; ks < 2; ++ks)
    qa[ks] = *(const short8*)&qb[lr * D_ + ks * 32 + lk * 8];

  f32x4 acc[4];
  float denomp[4];
#pragma unroll
  for (int n = 0; n < 4; ++n) acc[n] = (f32x4){0.f, 0.f, 0.f, 0.f};
#pragma unroll
  for (int r = 0; r < 4; ++r) denomp[r] = 0.f;

  for (int kv = 0; kv < T_; kv += 64) {
    // stage K tile [64][64] and Vt tile [64][64] (rows padded to 72)
#pragma unroll
    for (int i = 0; i < 2; ++i) {
      int cch = tid + i * 256; int row = cch >> 3, kc = cch & 7;
      *(short8*)&Ks[row * 72 + kc * 8] =
          *(const short8*)&kb[(size_t)(kv + row) * D_ + kc * 8];
      *(short8*)&Vts[row * 72 + kc * 8] =
          *(const short8*)&vb[(size_t)row * T_ + kv + kc * 8];
    }
    __syncthreads();

    // S = Q @ K^T  (raw q.k accumulated fp32)
    f32x4 s[4];
#pragma unroll
    for (int n = 0; n < 4; ++n) s[n] = (f32x4){0.f, 0.f, 0.f, 0.f};
#pragma unroll
    for (int kk = 0; kk < 2; ++kk) {
      short8 bk[4];
#pragma unroll
      for (int n = 0; n < 4; ++n)
        bk[n] = *(const short8*)&Ks[(n * 16 + lr) * 72 + kk * 32 + lk * 8];
#pragma unroll
      for (int n = 0; n < 4; ++n)
        s[n] = __builtin_amdgcn_mfma_f32_16x16x32_bf16(qa[kk], bk[n], s[n], 0, 0, 0);
    }

    // e = (s*inv + 5)^2 ; accumulate per-lane denom partial; stash bf16 E
#pragma unroll
    for (int n = 0; n < 4; ++n)
#pragma unroll
      for (int r = 0; r < 4; ++r) {
        float t = fmaf(s[n][r], inv, 5.0f);
        float e = t * t;
        denomp[r] += e;
        Es[w][(lk * 4 + r) * 72 + n * 16 + lr] = f2bf(e);
      }

    // PV: acc += E @ V   (A-frags from per-wave Es, B-frags from Vt)
#pragma unroll
    for (int kk = 0; kk < 2; ++kk) {
      short8 ea, vv[4];
      ea = *(const short8*)&Es[w][lr * 72 + kk * 32 + lk * 8];
#pragma unroll
      for (int n = 0; n < 4; ++n)
        vv[n] = *(const short8*)&Vts[(n * 16 + lr) * 72 + kk * 32 + lk * 8];
#pragma unroll
      for (int n = 0; n < 4; ++n)
        acc[n] = __builtin_amdgcn_mfma_f32_16x16x32_bf16(ea, vv[n], acc[n], 0, 0, 0);
    }
    __syncthreads();
  }

  // epilogue: reduce denom partials across the 16-lane column group (rows of
  // the C-tile live at lane group lk; reduction is over lr bits 1,2,4,8).
#pragma unroll
  for (int r = 0; r < 4; ++r) {
    float v = denomp[r];
    v += __shfl_xor(v, 1); v += __shfl_xor(v, 2);
    v += __shfl_xor(v, 4); v += __shfl_xor(v, 8);
    denomp[r] = v;
  }

#pragma unroll
  for (int n = 0; n < 4; ++n)
#pragma unroll
    for (int r = 0; r < 4; ++r) {
      int qrow = qt * 64 + w * 16 + lk * 4 + r;
      int d = n * 16 + lr;
      float o = acc[n][r] / (denomp[r] + 1e-6f);
      attn_out[((size_t)(b * T_ + qrow)) * C_ + h * D_ + d] = f2bf(o);
    }
}

// ---------------------------------------------------------------------------
extern "C" void kernel_launch(void* const* d_in, const int* in_sizes, int n_in,
                              void* d_out, int out_size, void* d_ws, size_t ws_size,
                              hipStream_t stream) {
  const float* x    = (const float*)d_in[0];
  const float* Wqkv = (const float*)d_in[1];
  const float* Wo   = (const float*)d_in[2];
  const float* tau  = (const float*)d_in[3];
  float* out = (float*)d_out;

  char* ws = (char*)d_ws;
  ushort_t* xb    = (ushort_t*)(ws);                 //  8,388,608 B
  ushort_t* wqkvT = (ushort_t*)(ws + 8388608);       //  6,291,456 B
  ushort_t* woT   = (ushort_t*)(ws + 14680064);      //  2,097,152 B
  ushort_t* qg    = (ushort_t*)(ws + 16777216);      //  8,388,608 B
  ushort_t* kg    = (ushort_t*)(ws + 25165824);      //  8,388,608 B
  ushort_t* ab    = (ushort_t*)(ws + 33554432);      //  8,388,608 B  (total ~42 MB)
  // v and vT scratch live in d_out (16,777,216 B) — consumed before gemm_out
  // overwrites d_out with the final fp32 result.
  ushort_t* vg  = (ushort_t*)d_out;
  ushort_t* vTg = (ushort_t*)d_out + 4194304;

  cast_x_kernel<<<4096, 256, 0, stream>>>(x, xb);
  transpose_cast_w<<<dim3(48, 16), 256, 0, stream>>>(Wqkv, wqkvT, 1024, 3072);
  transpose_cast_w<<<dim3(16, 16), 256, 0, stream>>>(Wo, woT, 1024, 1024);
  gemm_qkv<<<dim3(24, 32), 256, 0, stream>>>(xb, wqkvT, qg, kg, vg);
  transpose_v_kernel<<<dim3(32, 32), 256, 0, stream>>>(vg, vTg);
  attn_kernel<<<dim3(32, 32), 256, 0, stream>>>(qg, kg, vTg, tau, ab);
  gemm_out<<<dim3(8, 32), 256, 0, stream>>>(ab, woT, out);
}

// Round 3
// 126.110 us; speedup vs baseline: 1.3756x; 1.2353x over previous
//
#include <hip/hip_runtime.h>
#include <hip/hip_bf16.h>

// ---------------------------------------------------------------------------
// PlainSelfAttention (2quad, tau-scaled) on MI355X.
//  x[2,2048,1024] fp32, Wqkv[1024,3072], Wo[1024,1024], tau[16]
//  qkv GEMM -> per-head (s/(8*tau)+5)^2 attention (non-softmax, streaming)
//  -> Wo GEMM. All GEMMs bf16 MFMA with fp32 accumulation.
// R3: attn rewritten 32x32x16 swapped-QK^T, E fully in registers
//     (cvt_pk_bf16 + permlane32_swap), per-wave 64q, 2-way KV split,
//     epilogue LDS combine. No E LDS round-trip, no per-tile reduces.
// ---------------------------------------------------------------------------

typedef unsigned short ushort_t;
typedef __attribute__((ext_vector_type(8))) short short8;
typedef __attribute__((ext_vector_type(4))) float f32x4;
typedef __attribute__((ext_vector_type(16))) float f32x16;

#define B_      2
#define T_      2048
#define C_      1024
#define HEADS_  16
#define D_      64

union frag_u { unsigned u[4]; short8 s8; };

__device__ __forceinline__ ushort_t f2bf(float f) {
  __hip_bfloat16 h = __float2bfloat16(f);           // RNE
  return *reinterpret_cast<ushort_t*>(&h);
}

__device__ __forceinline__ unsigned cvt_pk_bf16(float lo, float hi) {
  unsigned r;
  asm("v_cvt_pk_bf16_f32 %0, %1, %2" : "=v"(r) : "v"(lo), "v"(hi));
  return r;
}

// v_permlane32_swap_b32: a' = lanes<32 ? a : b[lane-32];
//                        b' = lanes<32 ? a[lane+32] : b   (both modified)
__device__ __forceinline__ void permlane32_swap(unsigned &a, unsigned &b) {
  asm volatile("v_permlane32_swap_b32 %0, %1" : "+v"(a), "+v"(b));
}

__device__ __forceinline__ f32x16 zero16() {
  f32x16 z;
#pragma unroll
  for (int i = 0; i < 16; ++i) z[i] = 0.f;
  return z;
}

// -------------------------- cast x (fp32 -> bf16) --------------------------
__global__ __launch_bounds__(256) void cast_x_kernel(const float* __restrict__ x,
                                                     ushort_t* __restrict__ xb) {
  int i = blockIdx.x * 256 + threadIdx.x;
  float4 f = ((const float4*)x)[i];
  ushort_t* o = xb + (size_t)i * 4;
  o[0] = f2bf(f.x); o[1] = f2bf(f.y); o[2] = f2bf(f.z); o[3] = f2bf(f.w);
}

// ------------------ transpose + cast weights (fp32->bf16) ------------------
__global__ __launch_bounds__(256) void transpose_cast_w(const float* __restrict__ in,
                                                        ushort_t* __restrict__ out,
                                                        int R, int Cc) {
  __shared__ float tile[64][65];
  int rb = blockIdx.y, cb = blockIdx.x;
  int c = threadIdx.x & 63;
  int r0 = threadIdx.x >> 6;
#pragma unroll
  for (int i = 0; i < 16; ++i) {
    int r = r0 + i * 4;
    tile[r][c] = in[(size_t)(rb * 64 + r) * Cc + cb * 64 + c];
  }
  __syncthreads();
#pragma unroll
  for (int i = 0; i < 16; ++i) {
    int r = r0 + i * 4;
    out[(size_t)(cb * 64 + r) * R + rb * 64 + c] = f2bf(tile[c][r]);
  }
}

// ------------------------- transpose v -> vT (bf16) ------------------------
__global__ __launch_bounds__(256) void transpose_v_kernel(const ushort_t* __restrict__ v,
                                                          ushort_t* __restrict__ vT) {
  __shared__ ushort_t tile[64][72];
  int bh = blockIdx.y, tb = blockIdx.x;
  int c = threadIdx.x & 63;
  int r0 = threadIdx.x >> 6;
#pragma unroll
  for (int i = 0; i < 16; ++i) {
    int r = r0 + i * 4;
    tile[r][c] = v[((size_t)bh * T_ + tb * 64 + r) * D_ + c];
  }
  __syncthreads();
#pragma unroll
  for (int i = 0; i < 16; ++i) {
    int r = r0 + i * 4;
    vT[((size_t)bh * D_ + r) * T_ + tb * 64 + c] = tile[c][r];
  }
}

// -------------------- shared GEMM mainloop (bf16 MFMA) ---------------------
__device__ __forceinline__ void gemm_tile(const ushort_t* __restrict__ A,
                                          const ushort_t* __restrict__ Bt,
                                          int K, int tm, int tn,
                                          ushort_t* lds, f32x4 acc[4][4]) {
  const int tid = threadIdx.x;
  const int lane = tid & 63, wave = tid >> 6;
  const int wm = wave >> 1, wn = wave & 1;
  const int lr = lane & 15, lk = lane >> 4;
  ushort_t* As = lds;               // [128][72]
  ushort_t* Bs = lds + 128 * 72;    // [128][72]
  const ushort_t* Ag = A + (size_t)tm * 128 * K;
  const ushort_t* Bg = Bt + (size_t)tn * 128 * K;

  for (int kt = 0; kt < K; kt += 64) {
#pragma unroll
    for (int i = 0; i < 4; ++i) {
      int cch = tid + i * 256; int row = cch >> 3, kc = cch & 7;
      *(short8*)&As[row * 72 + kc * 8] =
          *(const short8*)&Ag[(size_t)row * K + kt + kc * 8];
    }
#pragma unroll
    for (int i = 0; i < 4; ++i) {
      int cch = tid + i * 256; int row = cch >> 3, kc = cch & 7;
      *(short8*)&Bs[row * 72 + kc * 8] =
          *(const short8*)&Bg[(size_t)row * K + kt + kc * 8];
    }
    __syncthreads();
#pragma unroll
    for (int kk = 0; kk < 64; kk += 32) {
      short8 a[4], b[4];
#pragma unroll
      for (int m = 0; m < 4; ++m)
        a[m] = *(const short8*)&As[(wm * 64 + m * 16 + lr) * 72 + kk + lk * 8];
#pragma unroll
      for (int n = 0; n < 4; ++n)
        b[n] = *(const short8*)&Bs[(wn * 64 + n * 16 + lr) * 72 + kk + lk * 8];
#pragma unroll
      for (int m = 0; m < 4; ++m)
#pragma unroll
        for (int n = 0; n < 4; ++n)
          acc[m][n] = __builtin_amdgcn_mfma_f32_16x16x32_bf16(a[m], b[n], acc[m][n], 0, 0, 0);
    }
    __syncthreads();
  }
}

// -------------------- GEMM1: qkv = xb @ Wqkv^T, scatter --------------------
__global__ __launch_bounds__(256) void gemm_qkv(const ushort_t* __restrict__ xb,
                                                const ushort_t* __restrict__ wT,
                                                ushort_t* __restrict__ qg,
                                                ushort_t* __restrict__ kg,
                                                ushort_t* __restrict__ vg) {
  __shared__ __align__(16) ushort_t lds[2 * 128 * 72];
  f32x4 acc[4][4];
#pragma unroll
  for (int m = 0; m < 4; ++m)
#pragma unroll
    for (int n = 0; n < 4; ++n) acc[m][n] = (f32x4){0.f, 0.f, 0.f, 0.f};

  gemm_tile(xb, wT, C_, blockIdx.y, blockIdx.x, lds, acc);

  const int lane = threadIdx.x & 63, wave = threadIdx.x >> 6;
  const int wm = wave >> 1, wn = wave & 1;
  const int lr = lane & 15, lk = lane >> 4;
#pragma unroll
  for (int m = 0; m < 4; ++m)
#pragma unroll
    for (int n = 0; n < 4; ++n)
#pragma unroll
      for (int r = 0; r < 4; ++r) {
        int row = blockIdx.y * 128 + wm * 64 + m * 16 + lk * 4 + r;  // = b*T + t
        int col = blockIdx.x * 128 + wn * 64 + n * 16 + lr;          // [0,3072)
        int b = row >> 11, t = row & 2047;
        int part = col >> 10, idx = col & 1023;
        int h = idx >> 6, j = idx & 63;
        ushort_t* dst = (part == 0) ? qg : (part == 1) ? kg : vg;
        dst[(((size_t)(b * HEADS_ + h)) * T_ + t) * D_ + j] = f2bf(acc[m][n][r]);
      }
}

// ---------------------- GEMM2: out = attn_bf16 @ Wo^T ----------------------
__global__ __launch_bounds__(256) void gemm_out(const ushort_t* __restrict__ ab,
                                                const ushort_t* __restrict__ woT,
                                                float* __restrict__ out) {
  __shared__ __align__(16) ushort_t lds[2 * 128 * 72];
  f32x4 acc[4][4];
#pragma unroll
  for (int m = 0; m < 4; ++m)
#pragma unroll
    for (int n = 0; n < 4; ++n) acc[m][n] = (f32x4){0.f, 0.f, 0.f, 0.f};

  gemm_tile(ab, woT, C_, blockIdx.y, blockIdx.x, lds, acc);

  const int lane = threadIdx.x & 63, wave = threadIdx.x >> 6;
  const int wm = wave >> 1, wn = wave & 1;
  const int lr = lane & 15, lk = lane >> 4;
#pragma unroll
  for (int m = 0; m < 4; ++m)
#pragma unroll
    for (int n = 0; n < 4; ++n)
#pragma unroll
      for (int r = 0; r < 4; ++r) {
        int row = blockIdx.y * 128 + wm * 64 + m * 16 + lk * 4 + r;
        int col = blockIdx.x * 128 + wn * 64 + n * 16 + lr;
        out[(size_t)row * C_ + col] = acc[m][n][r];
      }
}

// --------------------------- fused 2quad attention -------------------------
// Block: 4 waves = 2 q-groups (wq) x 2 KV-splits (wk). Per wave: 64 q-rows,
// half of each staged 128-wide KV tile. Swapped QK^T (mfma(K,Q), 32x32x16):
// lane holds E^T[k][q=lane&31] in regs -> denom is reg-local; PV A-frags
// built in-register via cvt_pk_bf16 + permlane32_swap. Epilogue combines the
// two KV halves through LDS (reusing the KV buffer).
__global__ __launch_bounds__(256, 2) void attn_kernel(const ushort_t* __restrict__ qg,
                                                      const ushort_t* __restrict__ kg,
                                                      const ushort_t* __restrict__ vTg,
                                                      const float* __restrict__ tau,
                                                      ushort_t* __restrict__ attn_out) {
  __shared__ __align__(16) ushort_t kvbuf[128 * 72 + 64 * 136];  // Ks | Vts (35.8 KB)
  __shared__ float denom_lds[2][2][2][32];                       // [wk][wq][qb][q]
  ushort_t* Ks  = kvbuf;             // [128 k][72]   rows = k, cols = d
  ushort_t* Vts = kvbuf + 128 * 72;  // [64 d][136]   rows = d, cols = k (128 wide)

  const int tid = threadIdx.x, lane = tid & 63;
  const int w = tid >> 6, wq = w >> 1, wk = w & 1;
  const int l31 = lane & 31, hi = lane >> 5, hi8 = hi * 8;
  const int qt = blockIdx.x, bh = blockIdx.y;
  const int b = bh >> 4, h = bh & 15;
  const float inv = 1.0f / (8.0f * tau[h]);   // sqrt(64)*tau

  const ushort_t* kb_ = kg  + (size_t)bh * T_ * D_;
  const ushort_t* vb_ = vTg + (size_t)bh * D_ * T_;
  const ushort_t* qp  = qg  + ((size_t)bh * T_ + qt * 128 + wq * 64) * D_;

  // Q B-frags in registers, loop-invariant: lane holds q-col = l31 (+qb*32),
  // d-elements dc*16 + hi*8 + j  -> contiguous b128 from global.
  short8 qf[2][4];
#pragma unroll
  for (int qb = 0; qb < 2; ++qb)
#pragma unroll
    for (int dc = 0; dc < 4; ++dc)
      qf[qb][dc] = *(const short8*)&qp[(qb * 32 + l31) * D_ + dc * 16 + hi8];

  f32x16 acc[2][2];   // [qb][db]: D[q=crow(r,hi)][d=db*32+l31]
  acc[0][0] = zero16(); acc[0][1] = zero16();
  acc[1][0] = zero16(); acc[1][1] = zero16();
  float denomp[2] = {0.f, 0.f};

  for (int rnd = 0; rnd < T_ / 128; ++rnd) {
    const int kv0 = rnd * 128;
    // stage K [128][64] and Vt [64][128] (both halves; all 256 threads)
#pragma unroll
    for (int i = 0; i < 4; ++i) {
      int cch = tid + i * 256;                 // 0..1023
      int row = cch >> 3, kc = cch & 7;
      *(short8*)&Ks[row * 72 + kc * 8] =
          *(const short8*)&kb_[(size_t)(kv0 + row) * D_ + kc * 8];
    }
#pragma unroll
    for (int i = 0; i < 4; ++i) {
      int cch = tid + i * 256;
      int row = cch >> 4, kc = cch & 15;
      *(short8*)&Vts[row * 136 + kc * 8] =
          *(const short8*)&vb_[(size_t)row * T_ + kv0 + kc * 8];
    }
    __syncthreads();

#pragma unroll
    for (int kb = 0; kb < 2; ++kb) {
      const int krow0 = wk * 64 + kb * 32;     // this wave's 32-k block
      // S^T = K-rows x Q-rows : D[k=crow(r,hi)][q=l31]
      f32x16 s[2]; s[0] = zero16(); s[1] = zero16();
#pragma unroll
      for (int dc = 0; dc < 4; ++dc) {
        short8 kf = *(const short8*)&Ks[(krow0 + l31) * 72 + dc * 16 + hi8];
        s[0] = __builtin_amdgcn_mfma_f32_32x32x16_bf16(kf, qf[0][dc], s[0], 0, 0, 0);
        s[1] = __builtin_amdgcn_mfma_f32_32x32x16_bf16(kf, qf[1][dc], s[1], 0, 0, 0);
      }

      // e = (s*inv+5)^2 in regs; reg-local denom; pack to PV A-frags:
      // chunk0 = {vdst(P0,P2), vdst(P1,P3), vsrc(P0,P2), vsrc(P1,P3)},
      // chunk1 same with P4..P7.  (P_p = cvt_pk(e[2p], e[2p+1]))
      frag_u ef[2][2];
#pragma unroll
      for (int qb = 0; qb < 2; ++qb) {
        float ev[16];
        float dsum = 0.f;
#pragma unroll
        for (int r = 0; r < 16; ++r) {
          float t = fmaf(s[qb][r], inv, 5.0f);
          ev[r] = t * t;
          dsum += ev[r];
        }
        denomp[qb] += dsum;
        unsigned P[8];
#pragma unroll
        for (int p = 0; p < 8; ++p) P[p] = cvt_pk_bf16(ev[2 * p], ev[2 * p + 1]);
        unsigned a0 = P[0], b0 = P[2]; permlane32_swap(a0, b0);
        unsigned a1 = P[1], b1 = P[3]; permlane32_swap(a1, b1);
        ef[qb][0].u[0] = a0; ef[qb][0].u[1] = a1; ef[qb][0].u[2] = b0; ef[qb][0].u[3] = b1;
        unsigned a2 = P[4], b2 = P[6]; permlane32_swap(a2, b2);
        unsigned a3 = P[5], b3 = P[7]; permlane32_swap(a3, b3);
        ef[qb][1].u[0] = a2; ef[qb][1].u[1] = a3; ef[qb][1].u[2] = b2; ef[qb][1].u[3] = b3;
      }

      // PV: acc[qb][db] += E[q][k-chunk] x V[k-chunk][d]
#pragma unroll
      for (int c = 0; c < 2; ++c)
#pragma unroll
        for (int db = 0; db < 2; ++db) {
          short8 vf = *(const short8*)&Vts[(db * 32 + l31) * 136 + krow0 + c * 16 + hi8];
          acc[0][db] = __builtin_amdgcn_mfma_f32_32x32x16_bf16(ef[0][c].s8, vf, acc[0][db], 0, 0, 0);
          acc[1][db] = __builtin_amdgcn_mfma_f32_32x32x16_bf16(ef[1][c].s8, vf, acc[1][db], 0, 0, 0);
        }
    }
    __syncthreads();
  }

  // ---------------- epilogue: combine KV halves, normalize ----------------
#pragma unroll
  for (int qb = 0; qb < 2; ++qb) {
    float v = denomp[qb];
    v += __shfl_xor(v, 32);                    // combine hi halves
    if (lane < 32) denom_lds[wk][wq][qb][l31] = v;
  }
  float* out_lds = (float*)kvbuf;              // [2 wq][64 q][64 d] fp32 (32 KB)
  if (wk == 1) {
#pragma unroll
    for (int qb = 0; qb < 2; ++qb)
#pragma unroll
      for (int db = 0; db < 2; ++db)
#pragma unroll
        for (int r = 0; r < 16; ++r) {
          int qr = qb * 32 + (r & 3) + 8 * (r >> 2) + 4 * hi;
          out_lds[(wq * 64 + qr) * 64 + db * 32 + l31] = acc[qb][db][r];
        }
  }
  __syncthreads();
  if (wk == 0) {
#pragma unroll
    for (int qb = 0; qb < 2; ++qb)
#pragma unroll
      for (int r = 0; r < 16; ++r) {
        int cr = (r & 3) + 8 * (r >> 2) + 4 * hi;
        int qr = qb * 32 + cr;
        float dt = denom_lds[0][wq][qb][cr] + denom_lds[1][wq][qb][cr];
        float dinv = 1.0f / (dt + 1e-6f);
#pragma unroll
        for (int db = 0; db < 2; ++db) {
          float val = acc[qb][db][r] + out_lds[(wq * 64 + qr) * 64 + db * 32 + l31];
          int grow = b * T_ + qt * 128 + wq * 64 + qr;
          attn_out[(size_t)grow * C_ + h * 64 + db * 32 + l31] = f2bf(val * dinv);
        }
      }
  }
}

// ---------------------------------------------------------------------------
extern "C" void kernel_launch(void* const* d_in, const int* in_sizes, int n_in,
                              void* d_out, int out_size, void* d_ws, size_t ws_size,
                              hipStream_t stream) {
  const float* x    = (const float*)d_in[0];
  const float* Wqkv = (const float*)d_in[1];
  const float* Wo   = (const float*)d_in[2];
  const float* tau  = (const float*)d_in[3];
  float* out = (float*)d_out;

  char* ws = (char*)d_ws;
  ushort_t* xb    = (ushort_t*)(ws);                 //  8,388,608 B
  ushort_t* wqkvT = (ushort_t*)(ws + 8388608);       //  6,291,456 B
  ushort_t* woT   = (ushort_t*)(ws + 14680064);      //  2,097,152 B
  ushort_t* qg    = (ushort_t*)(ws + 16777216);      //  8,388,608 B
  ushort_t* kg    = (ushort_t*)(ws + 25165824);      //  8,388,608 B
  ushort_t* ab    = (ushort_t*)(ws + 33554432);      //  8,388,608 B  (total ~42 MB)
  // v and vT scratch live in d_out (16,777,216 B) — consumed before gemm_out
  // overwrites d_out with the final fp32 result.
  ushort_t* vg  = (ushort_t*)d_out;
  ushort_t* vTg = (ushort_t*)d_out + 4194304;

  cast_x_kernel<<<4096, 256, 0, stream>>>(x, xb);
  transpose_cast_w<<<dim3(48, 16), 256, 0, stream>>>(Wqkv, wqkvT, 1024, 3072);
  transpose_cast_w<<<dim3(16, 16), 256, 0, stream>>>(Wo, woT, 1024, 1024);
  gemm_qkv<<<dim3(24, 32), 256, 0, stream>>>(xb, wqkvT, qg, kg, vg);
  transpose_v_kernel<<<dim3(32, 32), 256, 0, stream>>>(vg, vTg);
  attn_kernel<<<dim3(16, 32), 256, 0, stream>>>(qg, kg, vTg, tau, ab);
  gemm_out<<<dim3(8, 32), 256, 0, stream>>>(ab, woT, out);
}